// Round 9
// baseline (130.798 us; speedup 1.0000x reference)
//
#include <hip/hip_runtime.h>
#include <math.h>

// Directional Chamfer: sum_m min_n ||t_m - s_n||^2, SINGLE dispatch.
// q = 2 t.s - |s|^2 (maximize), d2 = |t|^2 - qmax.
// Phase A (all 1000 blocks): LDS pair-packed broadcast + v_pk_fma_f32 /
//   v_max3_f32, TPT=8 -> part[c][m] (plain stores).
// Phase B (50 ticket winners): 20-chunk group max -> qpart (plain loads; the
//   ACQ_REL ticket provides release/acquire ordering).
// Phase C (5 winners): 10-way max + d2 + fixed-order stripe sum.
// Phase D (1 winner): fixed-order sum of 5 stripe sums -> out.
// Tickets are module-scope __device__ counters: zeroed at module load, never
// touched by the ws poison, and each winner resets its counter to 0 after use
// (self-restoring invariant -> identical behavior on every call/replay).

typedef float v2 __attribute__((ext_vector_type(2)));

#define TPT 8
#define BLK 256
#define MPB (TPT * BLK)   // 2048 templates per block
#define CHUNK 100         // scan points per chunk (200*100 = 20000 exactly)
#define RED1 20           // chunks per ticket group
#define MAXG 64           // max groups per stripe
#define MAXSTRIPE 32

__device__ unsigned g_ctr1[MAXSTRIPE * MAXG];  // .bss -> zero at load
__device__ unsigned g_ctr2[MAXSTRIPE];
__device__ unsigned g_ctr3;

__device__ __forceinline__ v2 pk_fma(v2 a, v2 b, v2 c) {
    v2 d;
    asm("v_pk_fma_f32 %0, %1, %2, %3" : "=v"(d) : "v"(a), "v"(b), "v"(c));
    return d;
}
__device__ __forceinline__ float max3(float a, float b, float c) {
    float d;
    asm("v_max3_f32 %0, %1, %2, %3" : "=v"(d) : "v"(a), "v"(b), "v"(c));
    return d;
}

__global__ void __launch_bounds__(BLK) chamfer_all(
    const float* __restrict__ scan, const float* __restrict__ tmpl,
    float* __restrict__ part, float* __restrict__ qpart,
    float* __restrict__ stripeSums, float* __restrict__ out,
    int M, int N, int NC, int G, int GX) {
    __shared__ float4 lds4[(CHUNK + 1) / 2 * 2];
    float* ldsf = (float*)lds4;

    int bx = blockIdx.x;   // stripe (template range)
    int c = blockIdx.y;    // chunk
    int j0 = c * CHUNK;
    int cnt = N - j0;
    if (cnt > CHUNK) cnt = CHUNK;

    // ---- Phase A: pair sweep ----
    for (int i = threadIdx.x; i < cnt; i += BLK) {
        float x = scan[3 * (j0 + i) + 0];
        float y = scan[3 * (j0 + i) + 1];
        float z = scan[3 * (j0 + i) + 2];
        float* bp = &ldsf[(i >> 1) * 8];
        int h = i & 1;
        bp[0 + h] = 2.f * x;
        bp[2 + h] = 2.f * y;
        bp[4 + h] = 2.f * z;
        bp[6 + h] = -(x * x + y * y + z * z);
    }
    if ((cnt & 1) && threadIdx.x == 0) {  // pad odd tail so hi half is inert
        float* bp = &ldsf[(cnt >> 1) * 8];
        bp[1] = 0.f; bp[3] = 0.f; bp[5] = 0.f; bp[7] = -INFINITY;
    }
    __syncthreads();

    int base = bx * MPB + threadIdx.x;
    v2 txx[TPT], tyy[TPT], tzz[TPT];
    float q[TPT];
#pragma unroll
    for (int k = 0; k < TPT; ++k) {
        int m = base + k * BLK;
        float x = 0.f, y = 0.f, z = 0.f;
        if (m < M) {
            x = tmpl[3 * m + 0];
            y = tmpl[3 * m + 1];
            z = tmpl[3 * m + 2];
        }
        txx[k] = (v2){x, x};
        tyy[k] = (v2){y, y};
        tzz[k] = (v2){z, z};
        q[k] = -INFINITY;
    }

    int npair = (cnt + 1) >> 1;
#pragma unroll 2
    for (int p = 0; p < npair; ++p) {
        float4 a = lds4[2 * p + 0];  // broadcast: {2x0,2x1,2y0,2y1}
        float4 b = lds4[2 * p + 1];  // {2z0,2z1,-n0,-n1}
        v2 xx = (v2){a.x, a.y};
        v2 yy = (v2){a.z, a.w};
        v2 zz = (v2){b.x, b.y};
        v2 ww = (v2){b.z, b.w};
#pragma unroll
        for (int k = 0; k < TPT; ++k) {
            v2 r = pk_fma(tzz[k], zz, ww);
            r = pk_fma(tyy[k], yy, r);
            r = pk_fma(txx[k], xx, r);
            q[k] = max3(q[k], r.x, r.y);
        }
    }

#pragma unroll
    for (int k = 0; k < TPT; ++k) {
        int m = base + k * BLK;
        if (m < M) part[(size_t)c * M + m] = q[k];
    }

    // ---- Ticket 1: last block of this (stripe, chunk-group) ----
    int g = c / RED1;
    int c0 = g * RED1;
    int gsz = NC - c0;
    if (gsz > RED1) gsz = RED1;
    __shared__ int last1;
    __syncthreads();  // q-stores issued; release is on the fetch_add
    if (threadIdx.x == 0) {
        unsigned* ctr = &g_ctr1[bx * MAXG + g];
        unsigned t = __hip_atomic_fetch_add(ctr, 1u, __ATOMIC_ACQ_REL,
                                            __HIP_MEMORY_SCOPE_AGENT);
        int l = (t == (unsigned)(gsz - 1));
        if (l)  // reset for next replay (no arrivals remain this replay)
            __hip_atomic_store(ctr, 0u, __ATOMIC_RELAXED,
                               __HIP_MEMORY_SCOPE_AGENT);
        last1 = l;
    }
    __syncthreads();
    if (!last1) return;

    // ---- Phase B: group max over gsz chunks (plain cached loads) ----
    float qg[TPT];
#pragma unroll
    for (int k = 0; k < TPT; ++k) qg[k] = -INFINITY;
    for (int cc = c0; cc < c0 + gsz; ++cc) {
        const float* pr = part + (size_t)cc * M;
#pragma unroll
        for (int k = 0; k < TPT; ++k) {
            int m = base + k * BLK;
            if (m < M) qg[k] = fmaxf(qg[k], pr[m]);
        }
    }
#pragma unroll
    for (int k = 0; k < TPT; ++k) {
        int m = base + k * BLK;
        if (m < M) qpart[(size_t)g * M + m] = qg[k];
    }

    // ---- Ticket 2: last group of this stripe ----
    __shared__ int last2;
    __syncthreads();
    if (threadIdx.x == 0) {
        unsigned* ctr = &g_ctr2[bx];
        unsigned t = __hip_atomic_fetch_add(ctr, 1u, __ATOMIC_ACQ_REL,
                                            __HIP_MEMORY_SCOPE_AGENT);
        int l = (t == (unsigned)(G - 1));
        if (l)
            __hip_atomic_store(ctr, 0u, __ATOMIC_RELAXED,
                               __HIP_MEMORY_SCOPE_AGENT);
        last2 = l;
    }
    __syncthreads();
    if (!last2) return;

    // ---- Phase C: stripe max + d2 + fixed-order stripe sum ----
    float acc = 0.f;
#pragma unroll
    for (int k = 0; k < TPT; ++k) {
        int m = base + k * BLK;
        if (m < M) {
            float qmax = -INFINITY;
            for (int g2 = 0; g2 < G; ++g2)
                qmax = fmaxf(qmax, qpart[(size_t)g2 * M + m]);
            float x = tmpl[3 * m + 0];
            float y = tmpl[3 * m + 1];
            float z = tmpl[3 * m + 2];
            float d2 = fmaf(x, x, fmaf(y, y, z * z)) - qmax;
            if (d2 < 0.f) d2 = 0.f;
            acc += d2;
        }
    }
    for (int off = 32; off >= 1; off >>= 1) acc += __shfl_down(acc, off, 64);
    __shared__ float wsum[4];
    int lane = threadIdx.x & 63;
    int wid = threadIdx.x >> 6;
    if (lane == 0) wsum[wid] = acc;
    __syncthreads();

    __shared__ int last3;
    if (threadIdx.x == 0) {
        stripeSums[bx] = wsum[0] + wsum[1] + wsum[2] + wsum[3];
        unsigned t = __hip_atomic_fetch_add(&g_ctr3, 1u, __ATOMIC_ACQ_REL,
                                            __HIP_MEMORY_SCOPE_AGENT);
        int l = (t == (unsigned)(GX - 1));
        if (l)
            __hip_atomic_store(&g_ctr3, 0u, __ATOMIC_RELAXED,
                               __HIP_MEMORY_SCOPE_AGENT);
        last3 = l;
    }
    __syncthreads();
    if (!last3) return;

    // ---- Phase D: final fixed-order sum ----
    if (threadIdx.x == 0) {
        float s = 0.f;
        for (int b = 0; b < GX; ++b) s += stripeSums[b];
        out[0] = s;
    }
}

extern "C" void kernel_launch(void* const* d_in, const int* in_sizes, int n_in,
                              void* d_out, int out_size, void* d_ws,
                              size_t ws_size, hipStream_t stream) {
    const float* scan = (const float*)d_in[0];   // [N,3]
    const float* tmpl = (const float*)d_in[1];   // [M,3]
    int N = in_sizes[0] / 3;
    int M = in_sizes[1] / 3;
    float* out = (float*)d_out;

    int GX = (M + MPB - 1) / MPB;        // 5
    int NC = (N + CHUNK - 1) / CHUNK;    // 200
    int G = (NC + RED1 - 1) / RED1;      // 10

    char* ws = (char*)d_ws;
    float* stripeSums = (float*)ws;                         // GX floats
    float* qpart = (float*)(ws + 4096);                     // G*M floats
    size_t off = 4096 + ((size_t)G * M * 4 + 255) / 256 * 256;
    float* part = (float*)(ws + off);                       // NC*M floats

    dim3 grid(GX, NC);
    chamfer_all<<<grid, BLK, 0, stream>>>(scan, tmpl, part, qpart, stripeSums,
                                          out, M, N, NC, G, GX);
}

// Round 10
// 33.777 us; speedup vs baseline: 3.8724x; 3.8724x over previous
//
#include <hip/hip_runtime.h>
#include <math.h>

// Directional Chamfer: sum_m min_n ||t_m - s_n||^2.
// q = 2 t.s - |s|^2 (maximize), d2 = |t|^2 - qmax.
// 3 dispatches, no cross-block ordering anywhere:
//   1) hipMemsetAsync qmax_bits[M] = 0  (0 < mapped(f) for every float f)
//   2) main grid (5,100): LDS pair-packed chunk of 200 scan pts,
//      v_pk_fma_f32 + v_max3_f32, TPT=8; per-thread register max over the
//      chunk, then ONE relaxed fire-and-forget atomicMax per owned template
//      (order-preserving uint mapping -> bit-exact float max, deterministic).
//   3) final: single block, 1024 threads: unmap, d2, clamp, fixed-order
//      hierarchical sum -> out.

typedef float v2 __attribute__((ext_vector_type(2)));

#define TPT 8
#define BLK 256
#define MPB (TPT * BLK)   // 2048 templates per block-stripe
#define CHUNK 200         // scan points per chunk (100*200 = 20000 exactly)

__device__ __forceinline__ v2 pk_fma(v2 a, v2 b, v2 c) {
    v2 d;
    asm("v_pk_fma_f32 %0, %1, %2, %3" : "=v"(d) : "v"(a), "v"(b), "v"(c));
    return d;
}
__device__ __forceinline__ float max3(float a, float b, float c) {
    float d;
    asm("v_max3_f32 %0, %1, %2, %3" : "=v"(d) : "v"(a), "v"(b), "v"(c));
    return d;
}

// Order-preserving map float -> uint32 (monotone: a<b  <=>  map(a)<map(b)).
__device__ __forceinline__ unsigned map_f32(float f) {
    unsigned b = __float_as_uint(f);
    return (b & 0x80000000u) ? ~b : (b | 0x80000000u);
}
__device__ __forceinline__ float unmap_f32(unsigned u) {
    unsigned b = (u & 0x80000000u) ? (u ^ 0x80000000u) : ~u;
    return __uint_as_float(b);
}

__global__ void __launch_bounds__(BLK) chamfer_main(
    const float* __restrict__ scan, const float* __restrict__ tmpl,
    unsigned* __restrict__ qmax_bits, int M, int N) {
    __shared__ float4 lds4[CHUNK];  // 2 float4 per pair, CHUNK/2 pairs
    float* ldsf = (float*)lds4;

    int c = blockIdx.y;
    int j0 = c * CHUNK;
    int cnt = N - j0;
    if (cnt > CHUNK) cnt = CHUNK;

    for (int i = threadIdx.x; i < cnt; i += BLK) {
        float x = scan[3 * (j0 + i) + 0];
        float y = scan[3 * (j0 + i) + 1];
        float z = scan[3 * (j0 + i) + 2];
        float* bp = &ldsf[(i >> 1) * 8];
        int h = i & 1;
        bp[0 + h] = 2.f * x;
        bp[2 + h] = 2.f * y;
        bp[4 + h] = 2.f * z;
        bp[6 + h] = -(x * x + y * y + z * z);
    }
    if ((cnt & 1) && threadIdx.x == 0) {  // pad odd tail so hi half is inert
        float* bp = &ldsf[(cnt >> 1) * 8];
        bp[1] = 0.f; bp[3] = 0.f; bp[5] = 0.f; bp[7] = -INFINITY;
    }
    __syncthreads();

    int base = blockIdx.x * MPB + threadIdx.x;
    v2 txx[TPT], tyy[TPT], tzz[TPT];
    float q[TPT];
#pragma unroll
    for (int k = 0; k < TPT; ++k) {
        int m = base + k * BLK;
        float x = 0.f, y = 0.f, z = 0.f;
        if (m < M) {
            x = tmpl[3 * m + 0];
            y = tmpl[3 * m + 1];
            z = tmpl[3 * m + 2];
        }
        txx[k] = (v2){x, x};
        tyy[k] = (v2){y, y};
        tzz[k] = (v2){z, z};
        q[k] = -INFINITY;
    }

    int npair = (cnt + 1) >> 1;
#pragma unroll 2
    for (int p = 0; p < npair; ++p) {
        float4 a = lds4[2 * p + 0];  // broadcast: {2x0,2x1,2y0,2y1}
        float4 b = lds4[2 * p + 1];  // {2z0,2z1,-n0,-n1}
        v2 xx = (v2){a.x, a.y};
        v2 yy = (v2){a.z, a.w};
        v2 zz = (v2){b.x, b.y};
        v2 ww = (v2){b.z, b.w};
#pragma unroll
        for (int k = 0; k < TPT; ++k) {
            v2 r = pk_fma(tzz[k], zz, ww);
            r = pk_fma(tyy[k], yy, r);
            r = pk_fma(txx[k], xx, r);
            q[k] = max3(q[k], r.x, r.y);
        }
    }

    // One relaxed fire-and-forget atomic per owned template point.
#pragma unroll
    for (int k = 0; k < TPT; ++k) {
        int m = base + k * BLK;
        if (m < M) atomicMax(&qmax_bits[m], map_f32(q[k]));
    }
}

// Single block, 1024 threads: d2 + deterministic fixed-order sum.
__global__ void __launch_bounds__(1024) chamfer_final(
    const float* __restrict__ tmpl, const unsigned* __restrict__ qmax_bits,
    float* __restrict__ out, int M) {
    float acc = 0.f;
    for (int m = threadIdx.x; m < M; m += 1024) {
        float qmax = unmap_f32(qmax_bits[m]);
        float x = tmpl[3 * m + 0];
        float y = tmpl[3 * m + 1];
        float z = tmpl[3 * m + 2];
        float d2 = fmaf(x, x, fmaf(y, y, z * z)) - qmax;
        if (d2 < 0.f) d2 = 0.f;
        acc += d2;
    }
    for (int off = 32; off >= 1; off >>= 1) acc += __shfl_down(acc, off, 64);
    __shared__ float wsum[16];
    int lane = threadIdx.x & 63;
    int wid = threadIdx.x >> 6;
    if (lane == 0) wsum[wid] = acc;
    __syncthreads();
    if (threadIdx.x == 0) {
        float s = 0.f;
#pragma unroll
        for (int w = 0; w < 16; ++w) s += wsum[w];
        out[0] = s;
    }
}

extern "C" void kernel_launch(void* const* d_in, const int* in_sizes, int n_in,
                              void* d_out, int out_size, void* d_ws,
                              size_t ws_size, hipStream_t stream) {
    const float* scan = (const float*)d_in[0];   // [N,3]
    const float* tmpl = (const float*)d_in[1];   // [M,3]
    int N = in_sizes[0] / 3;
    int M = in_sizes[1] / 3;
    float* out = (float*)d_out;

    int GX = (M + MPB - 1) / MPB;        // 5
    int NC = (N + CHUNK - 1) / CHUNK;    // 100

    unsigned* qmax_bits = (unsigned*)d_ws;  // M u32

    hipMemsetAsync(qmax_bits, 0, (size_t)M * 4, stream);
    dim3 grid(GX, NC);
    chamfer_main<<<grid, BLK, 0, stream>>>(scan, tmpl, qmax_bits, M, N);
    chamfer_final<<<1, 1024, 0, stream>>>(tmpl, qmax_bits, out, M);
}

// Round 11
// 31.355 us; speedup vs baseline: 4.1715x; 1.0772x over previous
//
#include <hip/hip_runtime.h>
#include <math.h>

// Directional Chamfer: sum_m min_n ||t_m - s_n||^2.
// q = 2 t.s - |s|^2 (maximize), d2 = |t|^2 - qmax.
// 3 dispatches, no cross-block ordering (R9 lesson: acq_rel fences force
// cross-XCD L2 writeback/invalidate -> catastrophic; relaxed atomics don't):
//   1) hipMemsetAsync qmax_bits[M] = 0  (0 < mapped(f) for every float f)
//   2) main grid (10,100): LDS pair-packed chunk of 200 scan pts,
//      v_pk_fma_f32 + v_max3_f32, TPT=4 (atomic count = M*NC is TPT-
//      independent; TPT=4 doubles waves/SIMD to ~3.9 for LDS-latency hiding);
//      per-thread register max over chunk, then ONE relaxed fire-and-forget
//      atomicMax per owned template (order-preserving uint map -> bit-exact).
//   3) final: single block, 1024 threads: unmap, d2, clamp, fixed-order
//      hierarchical sum -> out (deterministic).

typedef float v2 __attribute__((ext_vector_type(2)));

#define TPT 4
#define BLK 256
#define MPB (TPT * BLK)   // 1024 templates per block-stripe
#define CHUNK 200         // scan points per chunk (100*200 = 20000 exactly)

__device__ __forceinline__ v2 pk_fma(v2 a, v2 b, v2 c) {
    v2 d;
    asm("v_pk_fma_f32 %0, %1, %2, %3" : "=v"(d) : "v"(a), "v"(b), "v"(c));
    return d;
}
__device__ __forceinline__ float max3(float a, float b, float c) {
    float d;
    asm("v_max3_f32 %0, %1, %2, %3" : "=v"(d) : "v"(a), "v"(b), "v"(c));
    return d;
}

// Order-preserving map float -> uint32 (monotone: a<b  <=>  map(a)<map(b)).
__device__ __forceinline__ unsigned map_f32(float f) {
    unsigned b = __float_as_uint(f);
    return (b & 0x80000000u) ? ~b : (b | 0x80000000u);
}
__device__ __forceinline__ float unmap_f32(unsigned u) {
    unsigned b = (u & 0x80000000u) ? (u ^ 0x80000000u) : ~u;
    return __uint_as_float(b);
}

__global__ void __launch_bounds__(BLK) chamfer_main(
    const float* __restrict__ scan, const float* __restrict__ tmpl,
    unsigned* __restrict__ qmax_bits, int M, int N) {
    __shared__ float4 lds4[CHUNK];  // 2 float4 per pair, CHUNK/2 pairs
    float* ldsf = (float*)lds4;

    int c = blockIdx.y;
    int j0 = c * CHUNK;
    int cnt = N - j0;
    if (cnt > CHUNK) cnt = CHUNK;

    for (int i = threadIdx.x; i < cnt; i += BLK) {
        float x = scan[3 * (j0 + i) + 0];
        float y = scan[3 * (j0 + i) + 1];
        float z = scan[3 * (j0 + i) + 2];
        float* bp = &ldsf[(i >> 1) * 8];
        int h = i & 1;
        bp[0 + h] = 2.f * x;
        bp[2 + h] = 2.f * y;
        bp[4 + h] = 2.f * z;
        bp[6 + h] = -(x * x + y * y + z * z);
    }
    if ((cnt & 1) && threadIdx.x == 0) {  // pad odd tail so hi half is inert
        float* bp = &ldsf[(cnt >> 1) * 8];
        bp[1] = 0.f; bp[3] = 0.f; bp[5] = 0.f; bp[7] = -INFINITY;
    }
    __syncthreads();

    int base = blockIdx.x * MPB + threadIdx.x;
    v2 txx[TPT], tyy[TPT], tzz[TPT];
    float q[TPT];
#pragma unroll
    for (int k = 0; k < TPT; ++k) {
        int m = base + k * BLK;
        float x = 0.f, y = 0.f, z = 0.f;
        if (m < M) {
            x = tmpl[3 * m + 0];
            y = tmpl[3 * m + 1];
            z = tmpl[3 * m + 2];
        }
        txx[k] = (v2){x, x};
        tyy[k] = (v2){y, y};
        tzz[k] = (v2){z, z};
        q[k] = -INFINITY;
    }

    int npair = (cnt + 1) >> 1;
#pragma unroll 4
    for (int p = 0; p < npair; ++p) {
        float4 a = lds4[2 * p + 0];  // broadcast: {2x0,2x1,2y0,2y1}
        float4 b = lds4[2 * p + 1];  // {2z0,2z1,-n0,-n1}
        v2 xx = (v2){a.x, a.y};
        v2 yy = (v2){a.z, a.w};
        v2 zz = (v2){b.x, b.y};
        v2 ww = (v2){b.z, b.w};
#pragma unroll
        for (int k = 0; k < TPT; ++k) {
            v2 r = pk_fma(tzz[k], zz, ww);
            r = pk_fma(tyy[k], yy, r);
            r = pk_fma(txx[k], xx, r);
            q[k] = max3(q[k], r.x, r.y);
        }
    }

    // One relaxed fire-and-forget atomic per owned template point.
#pragma unroll
    for (int k = 0; k < TPT; ++k) {
        int m = base + k * BLK;
        if (m < M) atomicMax(&qmax_bits[m], map_f32(q[k]));
    }
}

// Single block, 1024 threads: d2 + deterministic fixed-order sum.
__global__ void __launch_bounds__(1024) chamfer_final(
    const float* __restrict__ tmpl, const unsigned* __restrict__ qmax_bits,
    float* __restrict__ out, int M) {
    float acc = 0.f;
#pragma unroll 2
    for (int m = threadIdx.x; m < M; m += 1024) {
        float qmax = unmap_f32(qmax_bits[m]);
        float x = tmpl[3 * m + 0];
        float y = tmpl[3 * m + 1];
        float z = tmpl[3 * m + 2];
        float d2 = fmaf(x, x, fmaf(y, y, z * z)) - qmax;
        if (d2 < 0.f) d2 = 0.f;
        acc += d2;
    }
    for (int off = 32; off >= 1; off >>= 1) acc += __shfl_down(acc, off, 64);
    __shared__ float wsum[16];
    int lane = threadIdx.x & 63;
    int wid = threadIdx.x >> 6;
    if (lane == 0) wsum[wid] = acc;
    __syncthreads();
    if (threadIdx.x == 0) {
        float s = 0.f;
#pragma unroll
        for (int w = 0; w < 16; ++w) s += wsum[w];
        out[0] = s;
    }
}

extern "C" void kernel_launch(void* const* d_in, const int* in_sizes, int n_in,
                              void* d_out, int out_size, void* d_ws,
                              size_t ws_size, hipStream_t stream) {
    const float* scan = (const float*)d_in[0];   // [N,3]
    const float* tmpl = (const float*)d_in[1];   // [M,3]
    int N = in_sizes[0] / 3;
    int M = in_sizes[1] / 3;
    float* out = (float*)d_out;

    int GX = (M + MPB - 1) / MPB;        // 10
    int NC = (N + CHUNK - 1) / CHUNK;    // 100

    unsigned* qmax_bits = (unsigned*)d_ws;  // M u32

    hipMemsetAsync(qmax_bits, 0, (size_t)M * 4, stream);
    dim3 grid(GX, NC);
    chamfer_main<<<grid, BLK, 0, stream>>>(scan, tmpl, qmax_bits, M, N);
    chamfer_final<<<1, 1024, 0, stream>>>(tmpl, qmax_bits, out, M);
}